// Round 9
// baseline (378.792 us; speedup 1.0000x reference)
//
#include <hip/hip_runtime.h>
#include <hip/hip_bf16.h>

// ---------------------------------------------------------------------------
// SelfAttention: y = proj(attn(qkv(x)))   B=4 T=2048 C=1024 H=16 HD=64
// Inputs/outputs are FLOAT32 (per reference); pad_mask is int32.
// Internally: convert to bf16, MFMA 16x16x32 bf16, accumulate f32.
// GEMMs use the m97 structure: 128x128 tile, BK=64, global_load_lds(16B).
// ---------------------------------------------------------------------------

using short8  = __attribute__((ext_vector_type(8))) short;
using float4_ = __attribute__((ext_vector_type(4))) float;

#define Bb   4
#define Tt   2048
#define Cc   1024
#define Hh   16
#define HDd  64

// base-2 exp via the direct gfx950 intrinsic (one v_exp_f32).
#define EXP2F(x) __builtin_amdgcn_exp2f(x)

__device__ __forceinline__ float bf2f(unsigned short u) {
    union { float f; unsigned int i; } x; x.i = ((unsigned int)u) << 16; return x.f;
}
__device__ __forceinline__ unsigned short f2bf(float f) {
    union { float f; unsigned int i; } x; x.f = f;
    unsigned int r = x.i + 0x7fff + ((x.i >> 16) & 1);
    return (unsigned short)(r >> 16);
}
__device__ __forceinline__ float4_ bmfma(short8 a, short8 b, float4_ c) {
    return __builtin_amdgcn_mfma_f32_16x16x32_bf16(a, b, c, 0, 0, 0);
}
// async 16B global -> LDS (dest must be wave-uniform base + lane*16)
__device__ __forceinline__ void gl2lds16(const unsigned short* g, unsigned short* l) {
    __builtin_amdgcn_global_load_lds(
        (const __attribute__((address_space(1))) void*)g,
        (__attribute__((address_space(3))) void*)l, 16, 0, 0);
}

// ---------------------------------------------------------------------------
// x f32 -> bf16 (flat)
// ---------------------------------------------------------------------------
__global__ __launch_bounds__(256) void convert_f32_bf16(
    const float* __restrict__ in, unsigned short* __restrict__ out)
{
    size_t idx = ((size_t)blockIdx.x * 256 + threadIdx.x) * 8;
    float4_ f0 = *(const float4_*)&in[idx];
    float4_ f1 = *(const float4_*)&in[idx + 4];
    short8 h;
    h[0] = (short)f2bf(f0[0]); h[1] = (short)f2bf(f0[1]);
    h[2] = (short)f2bf(f0[2]); h[3] = (short)f2bf(f0[3]);
    h[4] = (short)f2bf(f1[0]); h[5] = (short)f2bf(f1[1]);
    h[6] = (short)f2bf(f1[2]); h[7] = (short)f2bf(f1[3]);
    *(short8*)&out[idx] = h;
}

// ---------------------------------------------------------------------------
// Transpose + convert: in f32 [R][Ccols] -> out bf16 [Ccols][R]
// ---------------------------------------------------------------------------
__global__ __launch_bounds__(256) void transpose_f32_bf16(
    const float* __restrict__ in, unsigned short* __restrict__ out,
    int R, int Ccols)
{
    __shared__ unsigned short tile[32][33];
    int c0 = blockIdx.x * 32, r0 = blockIdx.y * 32;
    int tx = threadIdx.x & 31, ty = threadIdx.x >> 5;   // ty 0..7
    for (int o = 0; o < 32; o += 8)
        tile[ty + o][tx] = f2bf(in[(size_t)(r0 + ty + o) * Ccols + c0 + tx]);
    __syncthreads();
    for (int o = 0; o < 32; o += 8)
        out[(size_t)(c0 + ty + o) * R + r0 + tx] = tile[tx][ty + o];
}

// ---------------------------------------------------------------------------
// m97-style GEMM main loop: C = A[M][K](bf16) * Bt[N][K](bf16)^T
// 128x128 block tile, BK=64, 4 waves each computing 64x64 via 4x4 MFMA.
// ---------------------------------------------------------------------------
#define GBK 64

__device__ __forceinline__ void gemm128_main(
    const unsigned short* __restrict__ A, const unsigned short* __restrict__ Bt,
    int K, int m0, int n0,
    unsigned short* As, unsigned short* Bs, float4_ acc[4][4])
{
    int tid  = threadIdx.x;
    int wave = tid >> 6, lane = tid & 63;
    int wm = (wave >> 1) * 64, wn = (wave & 1) * 64;
    int lr = lane & 15, lg = lane >> 4;
    int srow = tid >> 3;            // 0..31
    int scol = (tid & 7) * 8;       // 0..56

    for (int k0 = 0; k0 < K; k0 += GBK) {
        #pragma unroll
        for (int j = 0; j < 4; j++) {
            int row = j * 32 + srow;
            gl2lds16(&A [(size_t)(m0 + row) * K + k0 + scol], &As[row * GBK + scol]);
            gl2lds16(&Bt[(size_t)(n0 + row) * K + k0 + scol], &Bs[row * GBK + scol]);
        }
        __syncthreads();
        #pragma unroll
        for (int ks = 0; ks < GBK; ks += 32) {
            short8 af[4], bf[4];
            #pragma unroll
            for (int i = 0; i < 4; i++) {
                af[i] = *(const short8*)&As[(wm + i * 16 + lr) * GBK + ks + lg * 8];
                bf[i] = *(const short8*)&Bs[(wn + i * 16 + lr) * GBK + ks + lg * 8];
            }
            #pragma unroll
            for (int i = 0; i < 4; i++)
                #pragma unroll
                for (int j = 0; j < 4; j++)
                    acc[i][j] = bmfma(af[i], bf[j], acc[i][j]);
        }
        __syncthreads();
    }
}

// Q pre-scale: 1/sqrt(64) * log2(e) -> attn uses exp2 directly.
#define QSCALE 0.180336879f

__global__ __launch_bounds__(256) void gemm_qkv(
    const unsigned short* __restrict__ A,   // x: [8192][1024] bf16
    const unsigned short* __restrict__ Bt,  // w_attn^T: [3072][1024] bf16
    unsigned short* __restrict__ Q,         // [B][H][T][HD] bf16 (pre-scaled)
    unsigned short* __restrict__ Ko,
    unsigned short* __restrict__ V)
{
    __shared__ unsigned short As[128 * GBK];
    __shared__ unsigned short Bs[128 * GBK];
    int m0 = blockIdx.x * 128, n0 = blockIdx.y * 128;
    float4_ acc[4][4] = {};
    gemm128_main(A, Bt, 1024, m0, n0, As, Bs, acc);

    int lane = threadIdx.x & 63, wave = threadIdx.x >> 6;
    int wm = (wave >> 1) * 64, wn = (wave & 1) * 64;
    int lr = lane & 15, lg = lane >> 4;
    #pragma unroll
    for (int i = 0; i < 4; i++)
        #pragma unroll
        for (int j = 0; j < 4; j++) {
            int n = n0 + wn + 16 * j + lr;
            int which = n >> 10;
            int c = n & 1023;
            int h = c >> 6, d = c & 63;
            unsigned short* dst = (which == 0) ? Q : ((which == 1) ? Ko : V);
            float sc2 = (which == 0) ? QSCALE : 1.0f;
            #pragma unroll
            for (int r = 0; r < 4; r++) {
                int m = m0 + wm + 16 * i + lg * 4 + r;
                int b = m >> 11, t = m & 2047;
                dst[(((size_t)(b * Hh + h) * Tt) + t) * HDd + d] = f2bf(acc[i][j][r] * sc2);
            }
        }
}

__global__ __launch_bounds__(256) void gemm_proj(
    const unsigned short* __restrict__ A,   // y: [8192][1024] bf16
    const unsigned short* __restrict__ Bt,  // w_proj^T: [1024][1024] bf16
    const float* __restrict__ bias,         // [1024] f32
    float* __restrict__ Out)                // [8192][1024] f32
{
    __shared__ unsigned short As[128 * GBK];
    __shared__ unsigned short Bs[128 * GBK];
    int m0 = blockIdx.x * 128, n0 = blockIdx.y * 128;
    float4_ acc[4][4] = {};
    gemm128_main(A, Bt, 1024, m0, n0, As, Bs, acc);

    int lane = threadIdx.x & 63, wave = threadIdx.x >> 6;
    int wm = (wave >> 1) * 64, wn = (wave & 1) * 64;
    int lr = lane & 15, lg = lane >> 4;
    #pragma unroll
    for (int i = 0; i < 4; i++)
        #pragma unroll
        for (int j = 0; j < 4; j++) {
            int n = n0 + wn + 16 * j + lr;
            float bv = bias[n];
            #pragma unroll
            for (int r = 0; r < 4; r++) {
                int m = m0 + wm + 16 * i + lg * 4 + r;
                Out[(size_t)m * 1024 + n] = acc[i][j][r] + bv;
            }
        }
}

// ---------------------------------------------------------------------------
// Flash attention, SEQUENTIALLY-paired q-tiles: block (qpair,bh) processes
// q-tile qpair then q-tile 31-qpair as two sequential phases. Every block
// does exactly 33 tile-iterations (perfect balance, no tail), but only ONE
// tile's state is live at a time -> register pressure = round-6's spill-free
// single-tile kernel (VGPR ~64). P aliases Kt (safe: barrier after Kt reads).
// LDS 18.4 KB. 1024 equal blocks = 4/CU.
// Q pre-scaled by 1/8*log2(e): softmax uses exp2.
// ---------------------------------------------------------------------------
#define DPAD 72   // padded row stride (elems) = 144B

__global__ __launch_bounds__(256) void attn_fwd(
    const unsigned short* __restrict__ Q,   // [B][H][T][HD], pre-scaled
    const unsigned short* __restrict__ Kg,
    const unsigned short* __restrict__ Vg,
    const int* __restrict__ pad,            // [B][T]
    unsigned short* __restrict__ Y)         // [B][T][C]
{
    __shared__ unsigned short smem[128 * DPAD];
    unsigned short* Kt = smem;              // [key][d]   (aliased by P)
    unsigned short* Vt = smem + 64 * DPAD;  // [d][key-swizzled]

    int qpair = blockIdx.x;         // 0..15
    int bh = blockIdx.y;            // 0..63
    int b  = bh >> 4, h = bh & 15;
    const size_t base = (size_t)bh * Tt * HDd;
    int tid  = threadIdx.x;
    int wave = tid >> 6, lane = tid & 63;
    int lr = lane & 15, lg = lane >> 4;
    unsigned short* Pw = &Kt[wave * 16 * DPAD];   // per-wave P slice (Kt alias)
    const int* padRow = pad + b * Tt;

    for (int ph = 0; ph < 2; ph++) {
        int qb = ph ? (31 - qpair) : qpair;
        int q0 = qb * 64 + wave * 16;

        short8 qf0 = *(const short8*)&Q[base + (size_t)(q0 + lr) * HDd + lg * 8];
        short8 qf1 = *(const short8*)&Q[base + (size_t)(q0 + lr) * HDd + 32 + lg * 8];

        float m_i[4], l_i[4];
        float4_ o_acc[4];
        #pragma unroll
        for (int r = 0; r < 4; r++) { m_i[r] = -1e30f; l_i[r] = 0.f; }
        #pragma unroll
        for (int dt = 0; dt < 4; dt++) o_acc[dt] = (float4_){0.f, 0.f, 0.f, 0.f};

        for (int kt = 0; kt <= qb; kt++) {
            int k0 = kt * 64;
            // ---- stage K (as-is) and V (transposed, XOR key-block swizzle) ----
            {
                int r = tid >> 2, cbase = (tid & 3) * 8;
                #pragma unroll
                for (int half = 0; half < 2; half++) {
                    int c = cbase + half * 32;
                    *(short8*)&Kt[r * DPAD + c] =
                        *(const short8*)&Kg[base + (size_t)(k0 + r) * HDd + c];
                    alignas(16) unsigned short tmp[8];
                    *(short8*)tmp = *(const short8*)&Vg[base + (size_t)(k0 + r) * HDd + c];
                    #pragma unroll
                    for (int j = 0; j < 8; j++) {
                        int d = c + j;
                        Vt[d * DPAD + ((((r >> 3) ^ (d >> 3)) << 3) | (r & 7))] = tmp[j];
                    }
                }
            }
            __syncthreads();

            // pad mask as additive constant (per-lane key column)
            float pmask[4];
            #pragma unroll
            for (int nt = 0; nt < 4; nt++)
                pmask[nt] = (padRow[k0 + nt * 16 + lr] != 0) ? 0.f : -1e30f;

            // ---- S = Q K^T (Q pre-scaled), causal + pad mask ----
            float4_ s[4];
            #pragma unroll
            for (int nt = 0; nt < 4; nt++) {
                short8 kf0 = *(const short8*)&Kt[(nt * 16 + lr) * DPAD + lg * 8];
                short8 kf1 = *(const short8*)&Kt[(nt * 16 + lr) * DPAD + 32 + lg * 8];
                float4_ a = (float4_){0.f, 0.f, 0.f, 0.f};
                a = bmfma(qf0, kf0, a);
                a = bmfma(qf1, kf1, a);
                s[nt] = a;
            }
            if (k0 + 63 <= q0) {     // interior: no causal test needed
                #pragma unroll
                for (int nt = 0; nt < 4; nt++)
                    #pragma unroll
                    for (int r = 0; r < 4; r++)
                        s[nt][r] += pmask[nt];
            } else {                 // diagonal tile
                #pragma unroll
                for (int nt = 0; nt < 4; nt++) {
                    int key = k0 + nt * 16 + lr;
                    #pragma unroll
                    for (int r = 0; r < 4; r++) {
                        int qrow = q0 + lg * 4 + r;
                        float sv = s[nt][r] + pmask[nt];
                        if (key > qrow) sv = -1e30f;
                        s[nt][r] = sv;
                    }
                }
            }
            // ---- online softmax (base-2) ----
            float mn[4], alpha[4];
            #pragma unroll
            for (int r = 0; r < 4; r++) {
                float v = fmaxf(fmaxf(s[0][r], s[1][r]), fmaxf(s[2][r], s[3][r]));
                #pragma unroll
                for (int off = 1; off < 16; off <<= 1)
                    v = fmaxf(v, __shfl_xor(v, off, 64));
                float m_new = fmaxf(m_i[r], v);
                alpha[r] = EXP2F(m_i[r] - m_new);
                mn[r] = m_new;
            }
            float rsum[4] = {0.f, 0.f, 0.f, 0.f};
            #pragma unroll
            for (int nt = 0; nt < 4; nt++)
                #pragma unroll
                for (int r = 0; r < 4; r++) {
                    float p = EXP2F(s[nt][r] - mn[r]);
                    s[nt][r] = p;
                    rsum[r] += p;
                }
            #pragma unroll
            for (int r = 0; r < 4; r++) {
                float v = rsum[r];
                #pragma unroll
                for (int off = 1; off < 16; off <<= 1)
                    v += __shfl_xor(v, off, 64);
                l_i[r] = l_i[r] * alpha[r] + v;
                m_i[r] = mn[r];
            }

            __syncthreads();   // all waves done reading Kt -> safe to write P alias

            // ---- P: C-layout regs -> per-wave LDS slice (Kt alias) ----
            #pragma unroll
            for (int nt = 0; nt < 4; nt++)
                #pragma unroll
                for (int r = 0; r < 4; r++)
                    Pw[(lg * 4 + r) * DPAD + nt * 16 + lr] = f2bf(s[nt][r]);
            #pragma unroll
            for (int dt = 0; dt < 4; dt++)
                #pragma unroll
                for (int r = 0; r < 4; r++)
                    o_acc[dt][r] *= alpha[r];
            // ---- O += P @ V ----
            short8 pf0 = *(const short8*)&Pw[lr * DPAD + lg * 8];
            short8 pf1 = *(const short8*)&Pw[lr * DPAD + 32 + lg * 8];
            #pragma unroll
            for (int dt = 0; dt < 4; dt++) {
                int d = dt * 16 + lr;
                short8 vf0 = *(const short8*)&Vt[d * DPAD + ((lg ^ (d >> 3)) << 3)];
                short8 vf1 = *(const short8*)&Vt[d * DPAD + (((lg + 4) ^ (d >> 3)) << 3)];
                o_acc[dt] = bmfma(pf0, vf0, o_acc[dt]);
                o_acc[dt] = bmfma(pf1, vf1, o_acc[dt]);
            }
            __syncthreads();   // P + Vt consumed -> safe to restage
        }

        // ---- epilogue: Y[b][t][h*64+d] = O / l  (bf16) ----
        #pragma unroll
        for (int dt = 0; dt < 4; dt++)
            #pragma unroll
            for (int r = 0; r < 4; r++) {
                int qrow = q0 + lg * 4 + r;
                Y[((size_t)b * Tt + qrow) * Cc + h * HDd + dt * 16 + lr] =
                    f2bf(o_acc[dt][r] / l_i[r]);
            }
        __syncthreads();   // phase A's LDS fully consumed before phase B restages
    }
}

// ---------------------------------------------------------------------------
extern "C" void kernel_launch(void* const* d_in, const int* in_sizes, int n_in,
                              void* d_out, int out_size, void* d_ws, size_t ws_size,
                              hipStream_t stream)
{
    const float* x      = (const float*)d_in[0];
    const int*   pad    = (const int*)d_in[1];
    const float* w_attn = (const float*)d_in[2];
    const float* w_proj = (const float*)d_in[3];
    const float* b_proj = (const float*)d_in[4];
    float*       out    = (float*)d_out;

    // workspace carve-up (bf16 elems). Yb aliases Xb (x-bf16 dead after qkv).
    unsigned short* Wta = (unsigned short*)d_ws;            // 3072*1024
    unsigned short* Wtp = Wta + (size_t)3072 * 1024;        // 1024*1024
    unsigned short* Xb  = Wtp + (size_t)1024 * 1024;        // 8192*1024
    unsigned short* Yb  = Xb;                               // alias
    unsigned short* Qb  = Xb + (size_t)8192 * 1024;
    unsigned short* Kb  = Qb + (size_t)Bb * Hh * Tt * HDd;
    unsigned short* Vb  = Kb + (size_t)Bb * Hh * Tt * HDd;

    // 0) x f32 -> bf16
    convert_f32_bf16<<<dim3(4096), 256, 0, stream>>>(x, Xb);
    // 1) transpose+convert weights to bf16 [N][K]
    transpose_f32_bf16<<<dim3(3072 / 32, 1024 / 32), 256, 0, stream>>>(w_attn, Wta, 1024, 3072);
    transpose_f32_bf16<<<dim3(1024 / 32, 1024 / 32), 256, 0, stream>>>(w_proj, Wtp, 1024, 1024);
    // 2) qkv = x @ w_attn, scattered to head-major Q/K/V (bf16, Q pre-scaled)
    gemm_qkv<<<dim3(8192 / 128, 3072 / 128), 256, 0, stream>>>(Xb, Wta, Qb, Kb, Vb);
    // 3) flash attention, sequentially-paired q-tiles (perfect balance, no spill)
    attn_fwd<<<dim3(16, Bb * Hh), 256, 0, stream>>>(Qb, Kb, Vb, pad, Yb);
    // 4) out = y @ w_proj + b_proj (f32 out)
    gemm_proj<<<dim3(8192 / 128, 1024 / 128), 256, 0, stream>>>(Yb, Wtp, b_proj, out);
}

// Round 10
// 346.126 us; speedup vs baseline: 1.0944x; 1.0944x over previous
//
#include <hip/hip_runtime.h>
#include <hip/hip_bf16.h>

// ---------------------------------------------------------------------------
// SelfAttention: y = proj(attn(qkv(x)))   B=4 T=2048 C=1024 H=16 HD=64
// Inputs/outputs are FLOAT32 (per reference); pad_mask is int32.
// Internally: convert to bf16, MFMA 16x16x32 bf16, accumulate f32.
// GEMMs use the m97 structure: 128x128 tile, BK=64, global_load_lds(16B).
// attn: round-6 structure (single q-tile/block, 2048 blocks = 8/CU, P aliases
// Kt) + VALU diet (exp2, additive pmask, interior fast-path) + snake qb map
// for per-CU balance. Pairing (r4/r8/r9) is abandoned: it always costs either
// spill (interleaved) or occupancy+L2 locality (sequential) and loses.
// ---------------------------------------------------------------------------

using short8  = __attribute__((ext_vector_type(8))) short;
using float4_ = __attribute__((ext_vector_type(4))) float;

#define Bb   4
#define Tt   2048
#define Cc   1024
#define Hh   16
#define HDd  64

// base-2 exp via the direct gfx950 intrinsic (one v_exp_f32).
#define EXP2F(x) __builtin_amdgcn_exp2f(x)

__device__ __forceinline__ float bf2f(unsigned short u) {
    union { float f; unsigned int i; } x; x.i = ((unsigned int)u) << 16; return x.f;
}
__device__ __forceinline__ unsigned short f2bf(float f) {
    union { float f; unsigned int i; } x; x.f = f;
    unsigned int r = x.i + 0x7fff + ((x.i >> 16) & 1);
    return (unsigned short)(r >> 16);
}
__device__ __forceinline__ float4_ bmfma(short8 a, short8 b, float4_ c) {
    return __builtin_amdgcn_mfma_f32_16x16x32_bf16(a, b, c, 0, 0, 0);
}
// async 16B global -> LDS (dest must be wave-uniform base + lane*16)
__device__ __forceinline__ void gl2lds16(const unsigned short* g, unsigned short* l) {
    __builtin_amdgcn_global_load_lds(
        (const __attribute__((address_space(1))) void*)g,
        (__attribute__((address_space(3))) void*)l, 16, 0, 0);
}

// ---------------------------------------------------------------------------
// x f32 -> bf16 (flat)
// ---------------------------------------------------------------------------
__global__ __launch_bounds__(256) void convert_f32_bf16(
    const float* __restrict__ in, unsigned short* __restrict__ out)
{
    size_t idx = ((size_t)blockIdx.x * 256 + threadIdx.x) * 8;
    float4_ f0 = *(const float4_*)&in[idx];
    float4_ f1 = *(const float4_*)&in[idx + 4];
    short8 h;
    h[0] = (short)f2bf(f0[0]); h[1] = (short)f2bf(f0[1]);
    h[2] = (short)f2bf(f0[2]); h[3] = (short)f2bf(f0[3]);
    h[4] = (short)f2bf(f1[0]); h[5] = (short)f2bf(f1[1]);
    h[6] = (short)f2bf(f1[2]); h[7] = (short)f2bf(f1[3]);
    *(short8*)&out[idx] = h;
}

// ---------------------------------------------------------------------------
// Transpose + convert: in f32 [R][Ccols] -> out bf16 [Ccols][R]
// ---------------------------------------------------------------------------
__global__ __launch_bounds__(256) void transpose_f32_bf16(
    const float* __restrict__ in, unsigned short* __restrict__ out,
    int R, int Ccols)
{
    __shared__ unsigned short tile[32][33];
    int c0 = blockIdx.x * 32, r0 = blockIdx.y * 32;
    int tx = threadIdx.x & 31, ty = threadIdx.x >> 5;   // ty 0..7
    for (int o = 0; o < 32; o += 8)
        tile[ty + o][tx] = f2bf(in[(size_t)(r0 + ty + o) * Ccols + c0 + tx]);
    __syncthreads();
    for (int o = 0; o < 32; o += 8)
        out[(size_t)(c0 + ty + o) * R + r0 + tx] = tile[tx][ty + o];
}

// ---------------------------------------------------------------------------
// m97-style GEMM main loop: C = A[M][K](bf16) * Bt[N][K](bf16)^T
// 128x128 block tile, BK=64, 4 waves each computing 64x64 via 4x4 MFMA.
// ---------------------------------------------------------------------------
#define GBK 64

__device__ __forceinline__ void gemm128_main(
    const unsigned short* __restrict__ A, const unsigned short* __restrict__ Bt,
    int K, int m0, int n0,
    unsigned short* As, unsigned short* Bs, float4_ acc[4][4])
{
    int tid  = threadIdx.x;
    int wave = tid >> 6, lane = tid & 63;
    int wm = (wave >> 1) * 64, wn = (wave & 1) * 64;
    int lr = lane & 15, lg = lane >> 4;
    int srow = tid >> 3;            // 0..31
    int scol = (tid & 7) * 8;       // 0..56

    for (int k0 = 0; k0 < K; k0 += GBK) {
        #pragma unroll
        for (int j = 0; j < 4; j++) {
            int row = j * 32 + srow;
            gl2lds16(&A [(size_t)(m0 + row) * K + k0 + scol], &As[row * GBK + scol]);
            gl2lds16(&Bt[(size_t)(n0 + row) * K + k0 + scol], &Bs[row * GBK + scol]);
        }
        __syncthreads();
        #pragma unroll
        for (int ks = 0; ks < GBK; ks += 32) {
            short8 af[4], bf[4];
            #pragma unroll
            for (int i = 0; i < 4; i++) {
                af[i] = *(const short8*)&As[(wm + i * 16 + lr) * GBK + ks + lg * 8];
                bf[i] = *(const short8*)&Bs[(wn + i * 16 + lr) * GBK + ks + lg * 8];
            }
            #pragma unroll
            for (int i = 0; i < 4; i++)
                #pragma unroll
                for (int j = 0; j < 4; j++)
                    acc[i][j] = bmfma(af[i], bf[j], acc[i][j]);
        }
        __syncthreads();
    }
}

// Q pre-scale: 1/sqrt(64) * log2(e) -> attn uses exp2 directly.
#define QSCALE 0.180336879f

__global__ __launch_bounds__(256) void gemm_qkv(
    const unsigned short* __restrict__ A,   // x: [8192][1024] bf16
    const unsigned short* __restrict__ Bt,  // w_attn^T: [3072][1024] bf16
    unsigned short* __restrict__ Q,         // [B][H][T][HD] bf16 (pre-scaled)
    unsigned short* __restrict__ Ko,
    unsigned short* __restrict__ V)
{
    __shared__ unsigned short As[128 * GBK];
    __shared__ unsigned short Bs[128 * GBK];
    int m0 = blockIdx.x * 128, n0 = blockIdx.y * 128;
    float4_ acc[4][4] = {};
    gemm128_main(A, Bt, 1024, m0, n0, As, Bs, acc);

    int lane = threadIdx.x & 63, wave = threadIdx.x >> 6;
    int wm = (wave >> 1) * 64, wn = (wave & 1) * 64;
    int lr = lane & 15, lg = lane >> 4;
    #pragma unroll
    for (int i = 0; i < 4; i++)
        #pragma unroll
        for (int j = 0; j < 4; j++) {
            int n = n0 + wn + 16 * j + lr;
            int which = n >> 10;
            int c = n & 1023;
            int h = c >> 6, d = c & 63;
            unsigned short* dst = (which == 0) ? Q : ((which == 1) ? Ko : V);
            float sc2 = (which == 0) ? QSCALE : 1.0f;
            #pragma unroll
            for (int r = 0; r < 4; r++) {
                int m = m0 + wm + 16 * i + lg * 4 + r;
                int b = m >> 11, t = m & 2047;
                dst[(((size_t)(b * Hh + h) * Tt) + t) * HDd + d] = f2bf(acc[i][j][r] * sc2);
            }
        }
}

__global__ __launch_bounds__(256) void gemm_proj(
    const unsigned short* __restrict__ A,   // y: [8192][1024] bf16
    const unsigned short* __restrict__ Bt,  // w_proj^T: [1024][1024] bf16
    const float* __restrict__ bias,         // [1024] f32
    float* __restrict__ Out)                // [8192][1024] f32
{
    __shared__ unsigned short As[128 * GBK];
    __shared__ unsigned short Bs[128 * GBK];
    int m0 = blockIdx.x * 128, n0 = blockIdx.y * 128;
    float4_ acc[4][4] = {};
    gemm128_main(A, Bt, 1024, m0, n0, As, Bs, acc);

    int lane = threadIdx.x & 63, wave = threadIdx.x >> 6;
    int wm = (wave >> 1) * 64, wn = (wave & 1) * 64;
    int lr = lane & 15, lg = lane >> 4;
    #pragma unroll
    for (int i = 0; i < 4; i++)
        #pragma unroll
        for (int j = 0; j < 4; j++) {
            int n = n0 + wn + 16 * j + lr;
            float bv = bias[n];
            #pragma unroll
            for (int r = 0; r < 4; r++) {
                int m = m0 + wm + 16 * i + lg * 4 + r;
                Out[(size_t)m * 1024 + n] = acc[i][j][r] + bv;
            }
        }
}

// ---------------------------------------------------------------------------
// Flash attention: round-6 structure + VALU diet + snake qb map.
// One q-tile (64 rows) per block; 2048 blocks = 8/CU all co-resident;
// P aliases Kt (3 barriers/iter); LDS 18.4 KB; VGPR ~64 spill-free.
// Snake map: under round-robin block->CU dispatch each CU's 8 blocks sum to
// exactly 132 kt-iterations; still heavy-first; harmless if dispatch differs.
// ---------------------------------------------------------------------------
#define DPAD 72   // padded row stride (elems) = 144B

__global__ __launch_bounds__(256) void attn_fwd(
    const unsigned short* __restrict__ Q,   // [B][H][T][HD], pre-scaled
    const unsigned short* __restrict__ Kg,
    const unsigned short* __restrict__ Vg,
    const int* __restrict__ pad,            // [B][T]
    unsigned short* __restrict__ Y)         // [B][T][C]
{
    __shared__ unsigned short smem[128 * DPAD];
    unsigned short* Kt = smem;              // [key][d]   (aliased by P)
    unsigned short* Vt = smem + 64 * DPAD;  // [d][key-swizzled]

    int flat = blockIdx.x;          // 0..2047
    // snake qb mapping: slot s=flat>>8, quad r4=(flat>>6)&3, p=s>>1
    int slot = flat >> 8;
    int r4   = (flat >> 6) & 3;
    int p    = slot >> 1;
    int qb   = (slot & 1) ? (p * 4 + r4) : (31 - p * 4 - r4);
    int bh = flat & 63;
    int b  = bh >> 4, h = bh & 15;
    const size_t base = (size_t)bh * Tt * HDd;
    int tid  = threadIdx.x;
    int wave = tid >> 6, lane = tid & 63;
    int lr = lane & 15, lg = lane >> 4;
    int q0 = qb * 64 + wave * 16;
    unsigned short* Pw = &Kt[wave * 16 * DPAD];   // per-wave P slice (Kt alias)
    const int* padRow = pad + b * Tt;

    short8 qf0 = *(const short8*)&Q[base + (size_t)(q0 + lr) * HDd + lg * 8];
    short8 qf1 = *(const short8*)&Q[base + (size_t)(q0 + lr) * HDd + 32 + lg * 8];

    float m_i[4], l_i[4];
    float4_ o_acc[4];
    #pragma unroll
    for (int r = 0; r < 4; r++) { m_i[r] = -1e30f; l_i[r] = 0.f; }
    #pragma unroll
    for (int dt = 0; dt < 4; dt++) o_acc[dt] = (float4_){0.f, 0.f, 0.f, 0.f};

    for (int kt = 0; kt <= qb; kt++) {
        int k0 = kt * 64;
        // ---- stage K (as-is) and V (transposed, XOR key-block swizzle) ----
        {
            int r = tid >> 2, cbase = (tid & 3) * 8;
            #pragma unroll
            for (int half = 0; half < 2; half++) {
                int c = cbase + half * 32;
                *(short8*)&Kt[r * DPAD + c] =
                    *(const short8*)&Kg[base + (size_t)(k0 + r) * HDd + c];
                alignas(16) unsigned short tmp[8];
                *(short8*)tmp = *(const short8*)&Vg[base + (size_t)(k0 + r) * HDd + c];
                #pragma unroll
                for (int j = 0; j < 8; j++) {
                    int d = c + j;
                    Vt[d * DPAD + ((((r >> 3) ^ (d >> 3)) << 3) | (r & 7))] = tmp[j];
                }
            }
        }
        __syncthreads();

        // pad mask as additive constant (per-lane key column)
        float pmask[4];
        #pragma unroll
        for (int nt = 0; nt < 4; nt++)
            pmask[nt] = (padRow[k0 + nt * 16 + lr] != 0) ? 0.f : -1e30f;

        // ---- S = Q K^T (Q pre-scaled by 1/8*log2e), causal + pad mask ----
        float4_ s[4];
        #pragma unroll
        for (int nt = 0; nt < 4; nt++) {
            short8 kf0 = *(const short8*)&Kt[(nt * 16 + lr) * DPAD + lg * 8];
            short8 kf1 = *(const short8*)&Kt[(nt * 16 + lr) * DPAD + 32 + lg * 8];
            float4_ a = (float4_){0.f, 0.f, 0.f, 0.f};
            a = bmfma(qf0, kf0, a);
            a = bmfma(qf1, kf1, a);
            s[nt] = a;
        }
        if (k0 + 63 <= q0) {     // interior tile: causal test always false
            #pragma unroll
            for (int nt = 0; nt < 4; nt++)
                #pragma unroll
                for (int r = 0; r < 4; r++)
                    s[nt][r] += pmask[nt];
        } else {                 // diagonal tile
            #pragma unroll
            for (int nt = 0; nt < 4; nt++) {
                int key = k0 + nt * 16 + lr;
                #pragma unroll
                for (int r = 0; r < 4; r++) {
                    int qrow = q0 + lg * 4 + r;
                    float sv = s[nt][r] + pmask[nt];
                    if (key > qrow) sv = -1e30f;
                    s[nt][r] = sv;
                }
            }
        }
        // ---- online softmax (base-2) ----
        float mn[4], alpha[4];
        #pragma unroll
        for (int r = 0; r < 4; r++) {
            float v = fmaxf(fmaxf(s[0][r], s[1][r]), fmaxf(s[2][r], s[3][r]));
            #pragma unroll
            for (int off = 1; off < 16; off <<= 1)
                v = fmaxf(v, __shfl_xor(v, off, 64));
            float m_new = fmaxf(m_i[r], v);
            alpha[r] = EXP2F(m_i[r] - m_new);
            mn[r] = m_new;
        }
        float rsum[4] = {0.f, 0.f, 0.f, 0.f};
        #pragma unroll
        for (int nt = 0; nt < 4; nt++)
            #pragma unroll
            for (int r = 0; r < 4; r++) {
                float pexp = EXP2F(s[nt][r] - mn[r]);
                s[nt][r] = pexp;
                rsum[r] += pexp;
            }
        #pragma unroll
        for (int r = 0; r < 4; r++) {
            float v = rsum[r];
            #pragma unroll
            for (int off = 1; off < 16; off <<= 1)
                v += __shfl_xor(v, off, 64);
            l_i[r] = l_i[r] * alpha[r] + v;
            m_i[r] = mn[r];
        }

        __syncthreads();   // all waves done reading Kt -> safe to write P alias

        // ---- P: C-layout regs -> per-wave LDS slice (Kt alias) ----
        #pragma unroll
        for (int nt = 0; nt < 4; nt++)
            #pragma unroll
            for (int r = 0; r < 4; r++)
                Pw[(lg * 4 + r) * DPAD + nt * 16 + lr] = f2bf(s[nt][r]);
        #pragma unroll
        for (int dt = 0; dt < 4; dt++)
            #pragma unroll
            for (int r = 0; r < 4; r++)
                o_acc[dt][r] *= alpha[r];
        // ---- O += P @ V ----
        short8 pf0 = *(const short8*)&Pw[lr * DPAD + lg * 8];
        short8 pf1 = *(const short8*)&Pw[lr * DPAD + 32 + lg * 8];
        #pragma unroll
        for (int dt = 0; dt < 4; dt++) {
            int d = dt * 16 + lr;
            short8 vf0 = *(const short8*)&Vt[d * DPAD + ((lg ^ (d >> 3)) << 3)];
            short8 vf1 = *(const short8*)&Vt[d * DPAD + (((lg + 4) ^ (d >> 3)) << 3)];
            o_acc[dt] = bmfma(pf0, vf0, o_acc[dt]);
            o_acc[dt] = bmfma(pf1, vf1, o_acc[dt]);
        }
        __syncthreads();   // P + Vt consumed -> safe to restage
    }

    // ---- epilogue: Y[b][t][h*64+d] = O / l  (bf16) ----
    #pragma unroll
    for (int dt = 0; dt < 4; dt++)
        #pragma unroll
        for (int r = 0; r < 4; r++) {
            int qrow = q0 + lg * 4 + r;
            Y[((size_t)b * Tt + qrow) * Cc + h * HDd + dt * 16 + lr] =
                f2bf(o_acc[dt][r] / l_i[r]);
        }
}

// ---------------------------------------------------------------------------
extern "C" void kernel_launch(void* const* d_in, const int* in_sizes, int n_in,
                              void* d_out, int out_size, void* d_ws, size_t ws_size,
                              hipStream_t stream)
{
    const float* x      = (const float*)d_in[0];
    const int*   pad    = (const int*)d_in[1];
    const float* w_attn = (const float*)d_in[2];
    const float* w_proj = (const float*)d_in[3];
    const float* b_proj = (const float*)d_in[4];
    float*       out    = (float*)d_out;

    // workspace carve-up (bf16 elems). Yb aliases Xb (x-bf16 dead after qkv).
    unsigned short* Wta = (unsigned short*)d_ws;            // 3072*1024
    unsigned short* Wtp = Wta + (size_t)3072 * 1024;        // 1024*1024
    unsigned short* Xb  = Wtp + (size_t)1024 * 1024;        // 8192*1024
    unsigned short* Yb  = Xb;                               // alias
    unsigned short* Qb  = Xb + (size_t)8192 * 1024;
    unsigned short* Kb  = Qb + (size_t)Bb * Hh * Tt * HDd;
    unsigned short* Vb  = Kb + (size_t)Bb * Hh * Tt * HDd;

    // 0) x f32 -> bf16
    convert_f32_bf16<<<dim3(4096), 256, 0, stream>>>(x, Xb);
    // 1) transpose+convert weights to bf16 [N][K]
    transpose_f32_bf16<<<dim3(3072 / 32, 1024 / 32), 256, 0, stream>>>(w_attn, Wta, 1024, 3072);
    transpose_f32_bf16<<<dim3(1024 / 32, 1024 / 32), 256, 0, stream>>>(w_proj, Wtp, 1024, 1024);
    // 2) qkv = x @ w_attn, scattered to head-major Q/K/V (bf16, Q pre-scaled)
    gemm_qkv<<<dim3(8192 / 128, 3072 / 128), 256, 0, stream>>>(Xb, Wta, Qb, Kb, Vb);
    // 3) flash attention (2048 blocks, snake-balanced heavy-first)
    attn_fwd<<<dim3(2048), 256, 0, stream>>>(Qb, Kb, Vb, pad, Yb);
    // 4) out = y @ w_proj + b_proj (f32 out)
    gemm_proj<<<dim3(8192 / 128, 1024 / 128), 256, 0, stream>>>(Yb, Wtp, b_proj, out);
}